// Round 3
// baseline (54.543 us; speedup 1.0000x reference)
//
#include <hip/hip_runtime.h>

// SelfAttention: x[4,4096,64] f32; Wq,Wk[64,16]; Wv[64,64]; out[4,4096,64] f32.
// proj: bf16 MFMA with exact hi/lo split (f32-faithful), q pre-scaled by
//   1/sqrt(16)*log2e; outputs bf16 q,k row-major and v TRANSPOSED vt[b][dv][t].
// attn: flash with FIXED softmax max (M=24, safe: scores ~N(0,1.44^2) in log2
//   domain, max ~ +9) -> no max tree, no rescale, partials merge by summation.
//   Block = 16 waves (1024 thr), grid (64,4); block p owns q-tile pair
//   (p, 127-p) == exactly 65 KV tiles; waves split KV round-robin.
// V^T read straight from global (L2-resident 3MB) -- no LDS staging.

#define TSEQ 4096
#define NBATCH 4
#define MFIX 24.0f

typedef __attribute__((ext_vector_type(4)))  float fvec4;
typedef __attribute__((ext_vector_type(16))) float f32x16;
typedef __attribute__((ext_vector_type(4)))  short s16x4;
typedef __attribute__((ext_vector_type(8)))  short s16x8;

union I4S8 { int i[4]; s16x8 v; };

static __device__ __forceinline__ unsigned short f2bf(float f) {
    unsigned u = __float_as_uint(f);
    u += 0x7FFFu + ((u >> 16) & 1u);   // RNE
    return (unsigned short)(u >> 16);
}

static __device__ __forceinline__ int cvt_pk_bf16(float lo, float hi) {
    int r;
    asm("v_cvt_pk_bf16_f32 %0, %1, %2" : "=v"(r) : "v"(lo), "v"(hi));
    return r;
}

// ---------------------------------------------------------------------------
// Projection via MFMA. Block = 128 thr (2 waves), 64 x-rows; grid 256.
// x = xh + xl (bf16 pair, exact); W = Wh + Wl (bf16 pair, exact).
// x@W ~= xh·Wh + xh·Wl + xl·Wh  (dropped xl·Wl ~ 2^-18 relative).
// MFMA 32x32x16: A-frag row=lane&31 (x-row), B-frag col=lane&31 (out col);
// D: col=lane&31, row=(rr&3)+8*(rr>>2)+4*(lane>>5). Slot-paired A/B loads.
// ---------------------------------------------------------------------------
__global__ __launch_bounds__(128) void proj_kernel(
    const float* __restrict__ x,  const float* __restrict__ Wq,
    const float* __restrict__ Wk, const float* __restrict__ Wv,
    unsigned short* __restrict__ qb, unsigned short* __restrict__ kb,
    unsigned short* __restrict__ vt)
{
    __shared__ __align__(16) unsigned short Wh[96][72], Wl[96][72]; // [n][k]
    const int tid  = threadIdx.x;
    const int w    = tid >> 6;
    const int lane = tid & 63;
    const int col  = lane & 31;
    const int g    = lane >> 5;

    const float SCQ = 0.25f * 1.44269504088896340736f; // 1/sqrt(16)*log2(e)
    #pragma unroll
    for (int j = 0; j < 48; ++j) {
        const int flat = tid + 128 * j;          // 0..6143
        const int n = flat >> 6, k = flat & 63;
        float wv = (n < 16) ? Wq[k * 16 + n] * SCQ
                 : (n < 32) ? Wk[k * 16 + (n - 16)]
                            : Wv[k * 64 + (n - 32)];
        const unsigned short h = f2bf(wv);
        const float hf = __uint_as_float((unsigned)h << 16);
        Wh[n][k] = h;
        Wl[n][k] = f2bf(wv - hf);
    }
    __syncthreads();

    const int row0 = blockIdx.x * 64 + w * 32;
    const int arow = row0 + col;

    s16x8 xh[4], xl[4];
    #pragma unroll
    for (int kc = 0; kc < 4; ++kc) {
        const float* xp = x + (size_t)arow * 64 + kc * 16 + 8 * g;
        fvec4 xa = *(const fvec4*)(xp);
        fvec4 xb = *(const fvec4*)(xp + 4);
        I4S8 uh, ul;
        uh.i[0] = cvt_pk_bf16(xa[0], xa[1]);
        uh.i[1] = cvt_pk_bf16(xa[2], xa[3]);
        uh.i[2] = cvt_pk_bf16(xb[0], xb[1]);
        uh.i[3] = cvt_pk_bf16(xb[2], xb[3]);
        float l0 = xa[0] - __uint_as_float((unsigned)uh.i[0] << 16);
        float l1 = xa[1] - __uint_as_float((unsigned)uh.i[0] & 0xffff0000u);
        float l2 = xa[2] - __uint_as_float((unsigned)uh.i[1] << 16);
        float l3 = xa[3] - __uint_as_float((unsigned)uh.i[1] & 0xffff0000u);
        float l4 = xb[0] - __uint_as_float((unsigned)uh.i[2] << 16);
        float l5 = xb[1] - __uint_as_float((unsigned)uh.i[2] & 0xffff0000u);
        float l6 = xb[2] - __uint_as_float((unsigned)uh.i[3] << 16);
        float l7 = xb[3] - __uint_as_float((unsigned)uh.i[3] & 0xffff0000u);
        ul.i[0] = cvt_pk_bf16(l0, l1);
        ul.i[1] = cvt_pk_bf16(l2, l3);
        ul.i[2] = cvt_pk_bf16(l4, l5);
        ul.i[3] = cvt_pk_bf16(l6, l7);
        xh[kc] = uh.v; xl[kc] = ul.v;
    }

    f32x16 acc0 = (f32x16)0.0f, acc1 = (f32x16)0.0f, acc2 = (f32x16)0.0f;
    #pragma unroll
    for (int nt = 0; nt < 3; ++nt) {
        const int n = nt * 32 + col;
        f32x16 a = nt == 0 ? acc0 : (nt == 1 ? acc1 : acc2);
        #pragma unroll
        for (int kc = 0; kc < 4; ++kc) {
            s16x8 bh = *(const s16x8*)&Wh[n][kc * 16 + 8 * g];
            s16x8 bl = *(const s16x8*)&Wl[n][kc * 16 + 8 * g];
            a = __builtin_amdgcn_mfma_f32_32x32x16_bf16(xh[kc], bh, a, 0, 0, 0);
            a = __builtin_amdgcn_mfma_f32_32x32x16_bf16(xl[kc], bh, a, 0, 0, 0);
            a = __builtin_amdgcn_mfma_f32_32x32x16_bf16(xh[kc], bl, a, 0, 0, 0);
        }
        if (nt == 0) acc0 = a; else if (nt == 1) acc1 = a; else acc2 = a;
    }

    // -- store q/k (nt=0): lanes 0-15 -> q col, 16-31 -> k col
    {
        unsigned short* dst = (col < 16) ? (qb + col) : (kb + (col - 16));
        #pragma unroll
        for (int rr = 0; rr < 16; ++rr) {
            const int grow = row0 + (rr & 3) + 8 * (rr >> 2) + 4 * g;
            dst[(size_t)grow * 16] = f2bf(acc0[rr]);
        }
    }
    // -- store v transposed (nt=1,2): 8B packed stores along t
    const int bb = row0 >> 12;
    const int t0 = row0 & (TSEQ - 1);
    #pragma unroll
    for (int nt = 1; nt < 3; ++nt) {
        const f32x16 a = (nt == 1) ? acc1 : acc2;
        const int dv = (nt - 1) * 32 + col;
        unsigned short* vdst = vt + ((size_t)(bb * 64 + dv)) * TSEQ + t0 + 4 * g;
        #pragma unroll
        for (int rq = 0; rq < 4; ++rq) {
            int2 pkd;
            pkd.x = cvt_pk_bf16(a[4 * rq + 0], a[4 * rq + 1]);
            pkd.y = cvt_pk_bf16(a[4 * rq + 2], a[4 * rq + 3]);
            *(int2*)(vdst + 8 * rq) = pkd;
        }
    }
}

// ---------------------------------------------------------------------------
// One 64-key tile. MODE: 0 = full (no mask), 1 = diag even-i (only first 32
// keys live, triangular), 2 = diag odd-i (first 32 full, second triangular).
// Mask predicate in both diag cases: key live iff drow <= col.
// ---------------------------------------------------------------------------
template<int MODE>
static __device__ __forceinline__ void do_tile(
    const unsigned short* kp, const unsigned short* vr0, const unsigned short* vr1,
    const s16x8 qf, const int col, const int g,
    f32x16& o0, f32x16& o1, float& lsum)
{
    const int NC = (MODE == 1) ? 2 : 4;   // 16-key chunks for PV
    s16x8 kf0 = *(const s16x8*)(kp);
    s16x8 kf1;
    if (MODE != 1) kf1 = *(const s16x8*)(kp + 512);
    s16x4 va[2][4][2];
    #pragma unroll
    for (int mt = 0; mt < 2; ++mt) {
        const unsigned short* vr = mt ? vr1 : vr0;
        #pragma unroll
        for (int c = 0; c < NC; ++c) {
            va[mt][c][0] = *(const s16x4*)(vr + 16 * c + 4 * g);
            va[mt][c][1] = *(const s16x4*)(vr + 16 * c + 8 + 4 * g);
        }
    }
    f32x16 s0 = __builtin_amdgcn_mfma_f32_32x32x16_bf16(kf0, qf, (f32x16)0.0f, 0, 0, 0);
    f32x16 s1;
    if (MODE != 1) s1 = __builtin_amdgcn_mfma_f32_32x32x16_bf16(kf1, qf, (f32x16)0.0f, 0, 0, 0);

    float e[32];
    float ps[4] = {0.f, 0.f, 0.f, 0.f};
    #pragma unroll
    for (int rr = 0; rr < 16; ++rr) {
        const int drow = (rr & 3) + 8 * (rr >> 2) + 4 * g;
        float e0 = exp2f(s0[rr] - MFIX);
        if (MODE == 1) e0 = (drow <= col) ? e0 : 0.f;
        float e1 = 0.f;
        if (MODE != 1) {
            e1 = exp2f(s1[rr] - MFIX);
            if (MODE == 2) e1 = (drow <= col) ? e1 : 0.f;
        }
        e[rr] = e0;
        e[16 + rr] = e1;
        ps[rr & 3] += e0 + e1;
    }
    lsum += (ps[0] + ps[1]) + (ps[2] + ps[3]);

    int pw[16];
    #pragma unroll
    for (int j = 0; j < (MODE == 1 ? 8 : 16); ++j)
        pw[j] = cvt_pk_bf16(e[2 * j], e[2 * j + 1]);

    #pragma unroll
    for (int mt = 0; mt < 2; ++mt) {
        f32x16 oacc = mt ? o1 : o0;
        #pragma unroll
        for (int c = 0; c < NC; ++c) {
            s16x8 af = __builtin_shufflevector(va[mt][c][0], va[mt][c][1],
                                               0, 1, 2, 3, 4, 5, 6, 7);
            I4S8 pu;
            pu.i[0] = pw[4 * c + 0]; pu.i[1] = pw[4 * c + 1];
            pu.i[2] = pw[4 * c + 2]; pu.i[3] = pw[4 * c + 3];
            oacc = __builtin_amdgcn_mfma_f32_32x32x16_bf16(af, pu.v, oacc, 0, 0, 0);
        }
        if (mt) o1 = oacc; else o0 = oacc;
    }
}

// ---------------------------------------------------------------------------
// Flash attention. 1024 thr = 16 waves; grid (64, NBATCH). Block p does
// q-tiles p and 127-p (65 KV tiles total). Wave w: kt = w, w+16, ...
// Fixed-M => partials merge by SUMMATION (no max merge).
// ---------------------------------------------------------------------------
__global__ __launch_bounds__(1024) void attn_kernel(
    const unsigned short* __restrict__ qb, const unsigned short* __restrict__ kb,
    const unsigned short* __restrict__ vt, float* __restrict__ out)
{
    __shared__ float pl[16][32];
    __shared__ __align__(16) float pO[2048][18];  // [dv*32+q][ww], 144 KB
    __shared__ float outS[32][66];                // store bounce (coalescing)

    const int tid  = threadIdx.x;
    const int w    = tid >> 6;
    const int lane = tid & 63;
    const int col  = lane & 31;
    const int g    = lane >> 5;
    const int b    = blockIdx.y;
    const int p    = blockIdx.x;

    const unsigned short* const vrow0 = vt + ((size_t)(b * 64) + col) * TSEQ;
    const unsigned short* const vrow1 = vrow0 + (size_t)32 * TSEQ;
    const unsigned short* const kbase = kb + (size_t)b * TSEQ * 16;

    for (int half = 0; half < 2; ++half) {
        const int i  = half ? (127 - p) : p;
        const int q0 = i * 32;
        const int n  = (i + 2) >> 1;          // tiles covering keys 0..q0+31

        const s16x8 qf = *(const s16x8*)(qb + ((size_t)(b * TSEQ) + q0 + col) * 16 + 8 * g);

        f32x16 o0 = (f32x16)0.0f, o1 = (f32x16)0.0f;
        float lsum = 0.f;

        int kt = w;
        for (; kt + 1 < n; kt += 16) {
            const int k0 = kt << 6;
            do_tile<0>(kbase + ((size_t)(k0 + col)) * 16 + 8 * g,
                       vrow0 + k0, vrow1 + k0, qf, col, g, o0, o1, lsum);
        }
        if (kt == n - 1) {                    // this wave owns the diagonal tile
            const int k0 = kt << 6;
            const unsigned short* kp = kbase + ((size_t)(k0 + col)) * 16 + 8 * g;
            if (i & 1) do_tile<2>(kp, vrow0 + k0, vrow1 + k0, qf, col, g, o0, o1, lsum);
            else       do_tile<1>(kp, vrow0 + k0, vrow1 + k0, qf, col, g, o0, o1, lsum);
        }
        lsum += __shfl_xor(lsum, 32);

        // -- write partials (idle waves write zeros: harmless under summation)
        if (g == 0) pl[w][col] = lsum;
        #pragma unroll
        for (int mt = 0; mt < 2; ++mt) {
            const f32x16 oa = mt ? o1 : o0;
            #pragma unroll
            for (int rr = 0; rr < 16; ++rr) {
                const int dv = mt * 32 + (rr & 3) + 8 * (rr >> 2) + 4 * g;
                pO[dv * 32 + col][w] = oa[rr];
            }
        }
        __syncthreads();

        // -- 16-way sum merge: thread handles (q = tid&31, dv = tid>>5 [+32])
        {
            const int q   = tid & 31;
            const int dvh = tid >> 5;
            float L = 0.f;
            #pragma unroll
            for (int ww = 0; ww < 16; ++ww) L += pl[ww][q];
            const float inv = 1.0f / L;
            #pragma unroll
            for (int pass = 0; pass < 2; ++pass) {
                const int dv = dvh + 32 * pass;
                const float* prow = pO[dv * 32 + q];
                float s = 0.f;
                #pragma unroll
                for (int c = 0; c < 8; ++c) {
                    float2 v2 = *(const float2*)(prow + 2 * c);
                    s += v2.x + v2.y;
                }
                outS[q][dv] = s * inv;
            }
        }
        __syncthreads();

        // -- coalesced store: thread (q2 = tid>>5, dvp = (tid&31)*2)
        {
            const int q2  = tid >> 5;
            const int dvp = (tid & 31) * 2;
            float2 v2 = *(const float2*)&outS[q2][dvp];
            *(float2*)(out + ((size_t)(b * TSEQ) + q0 + q2) * 64 + dvp) = v2;
        }
        // pO reuse in next half is safe: its reads completed before the
        // barrier above; next half's writes come after it.
    }
}

// ---------------------------------------------------------------------------
extern "C" void kernel_launch(void* const* d_in, const int* in_sizes, int n_in,
                              void* d_out, int out_size, void* d_ws, size_t ws_size,
                              hipStream_t stream) {
    const float* x  = (const float*)d_in[0];
    const float* Wq = (const float*)d_in[1];
    const float* Wk = (const float*)d_in[2];
    const float* Wv = (const float*)d_in[3];

    // workspace: q (512KiB) | k (512KiB) | v^T (2MiB) = 3 MiB
    unsigned short* qb = (unsigned short*)d_ws;
    unsigned short* kb = qb + (size_t)NBATCH * TSEQ * 16;
    unsigned short* vt = kb + (size_t)NBATCH * TSEQ * 16;
    float* out = (float*)d_out;

    proj_kernel<<<dim3((NBATCH * TSEQ) / 64), 128, 0, stream>>>(x, Wq, Wk, Wv, qb, kb, vt);
    attn_kernel<<<dim3(64, NBATCH), 1024, 0, stream>>>(qb, kb, vt, out);
}

// Round 4
// 31.614 us; speedup vs baseline: 1.7253x; 1.7253x over previous
//
#include <hip/hip_runtime.h>

// SelfAttention: x[4,4096,64] f32; Wq,Wk[64,16]; Wv[64,64]; out[4,4096,64] f32.
// proj: bf16 MFMA with exact hi/lo split (f32-faithful), q pre-scaled by
//   1/sqrt(16)*log2e; outputs bf16 q,k row-major and V in MFMA *fragment
//   order* vf[b][kt][c][mt][lane][8] so attention's PV A-operand loads are
//   fully coalesced (64 lanes x 16B = 1KB contiguous per load).
// attn: flash with FIXED softmax max (M=24; scores ~N(0,1.44^2) in log2
//   domain) -> no max tree, no rescale, partials merge by summation.
//   Block = 16 waves (1024 thr), grid (64,4); block p owns q-tile pair
//   (p, 127-p) == exactly 65 KV tiles; waves split KV round-robin.

#define TSEQ 4096
#define NBATCH 4
#define MFIX 24.0f

typedef __attribute__((ext_vector_type(4)))  float fvec4;
typedef __attribute__((ext_vector_type(16))) float f32x16;
typedef __attribute__((ext_vector_type(4)))  short s16x4;
typedef __attribute__((ext_vector_type(8)))  short s16x8;

union I4S8 { int i[4]; s16x8 v; };

static __device__ __forceinline__ unsigned short f2bf(float f) {
    unsigned u = __float_as_uint(f);
    u += 0x7FFFu + ((u >> 16) & 1u);   // RNE
    return (unsigned short)(u >> 16);
}

static __device__ __forceinline__ int cvt_pk_bf16(float lo, float hi) {
    int r;
    asm("v_cvt_pk_bf16_f32 %0, %1, %2" : "=v"(r) : "v"(lo), "v"(hi));
    return r;
}

// ---------------------------------------------------------------------------
// Projection via MFMA. Block = 128 thr (2 waves) = 64 x-rows = one attn KV
// tile; grid 256 (= batch*64). x = xh+xl, W = Wh+Wl (bf16 splits, exact);
// x@W ~= xh·Wh + xh·Wl + xl·Wh  (dropped xl·Wl ~ 2^-18 relative).
// D-layout per lane == attn A-frag layout, so V stores go out in fragment
// order with no cross-lane ops: vf[(((b*64+kt)*4+c)*2+mt)*64+lane][8].
// ---------------------------------------------------------------------------
__global__ __launch_bounds__(128) void proj_kernel(
    const float* __restrict__ x,  const float* __restrict__ Wq,
    const float* __restrict__ Wk, const float* __restrict__ Wv,
    unsigned short* __restrict__ qb, unsigned short* __restrict__ kb,
    unsigned short* __restrict__ vf)
{
    __shared__ __align__(16) unsigned short Wh[96][72], Wl[96][72]; // [n][k]
    const int tid  = threadIdx.x;
    const int w    = tid >> 6;
    const int lane = tid & 63;
    const int col  = lane & 31;
    const int g    = lane >> 5;

    const float SCQ = 0.25f * 1.44269504088896340736f; // 1/sqrt(16)*log2(e)
    #pragma unroll
    for (int j = 0; j < 48; ++j) {
        const int flat = tid + 128 * j;          // 0..6143
        const int n = flat >> 6, k = flat & 63;
        float wv = (n < 16) ? Wq[k * 16 + n] * SCQ
                 : (n < 32) ? Wk[k * 16 + (n - 16)]
                            : Wv[k * 64 + (n - 32)];
        const unsigned short h = f2bf(wv);
        const float hf = __uint_as_float((unsigned)h << 16);
        Wh[n][k] = h;
        Wl[n][k] = f2bf(wv - hf);
    }
    __syncthreads();

    const int row0 = blockIdx.x * 64 + w * 32;
    const int arow = row0 + col;

    s16x8 xh[4], xl[4];
    #pragma unroll
    for (int kc = 0; kc < 4; ++kc) {
        const float* xp = x + (size_t)arow * 64 + kc * 16 + 8 * g;
        fvec4 xa = *(const fvec4*)(xp);
        fvec4 xb = *(const fvec4*)(xp + 4);
        I4S8 uh, ul;
        uh.i[0] = cvt_pk_bf16(xa[0], xa[1]);
        uh.i[1] = cvt_pk_bf16(xa[2], xa[3]);
        uh.i[2] = cvt_pk_bf16(xb[0], xb[1]);
        uh.i[3] = cvt_pk_bf16(xb[2], xb[3]);
        float l0 = xa[0] - __uint_as_float((unsigned)uh.i[0] << 16);
        float l1 = xa[1] - __uint_as_float((unsigned)uh.i[0] & 0xffff0000u);
        float l2 = xa[2] - __uint_as_float((unsigned)uh.i[1] << 16);
        float l3 = xa[3] - __uint_as_float((unsigned)uh.i[1] & 0xffff0000u);
        float l4 = xb[0] - __uint_as_float((unsigned)uh.i[2] << 16);
        float l5 = xb[1] - __uint_as_float((unsigned)uh.i[2] & 0xffff0000u);
        float l6 = xb[2] - __uint_as_float((unsigned)uh.i[3] << 16);
        float l7 = xb[3] - __uint_as_float((unsigned)uh.i[3] & 0xffff0000u);
        ul.i[0] = cvt_pk_bf16(l0, l1);
        ul.i[1] = cvt_pk_bf16(l2, l3);
        ul.i[2] = cvt_pk_bf16(l4, l5);
        ul.i[3] = cvt_pk_bf16(l6, l7);
        xh[kc] = uh.v; xl[kc] = ul.v;
    }

    f32x16 acc0 = (f32x16)0.0f, acc1 = (f32x16)0.0f, acc2 = (f32x16)0.0f;
    #pragma unroll
    for (int nt = 0; nt < 3; ++nt) {
        const int n = nt * 32 + col;
        f32x16 a = nt == 0 ? acc0 : (nt == 1 ? acc1 : acc2);
        #pragma unroll
        for (int kc = 0; kc < 4; ++kc) {
            s16x8 bh = *(const s16x8*)&Wh[n][kc * 16 + 8 * g];
            s16x8 bl = *(const s16x8*)&Wl[n][kc * 16 + 8 * g];
            a = __builtin_amdgcn_mfma_f32_32x32x16_bf16(xh[kc], bh, a, 0, 0, 0);
            a = __builtin_amdgcn_mfma_f32_32x32x16_bf16(xl[kc], bh, a, 0, 0, 0);
            a = __builtin_amdgcn_mfma_f32_32x32x16_bf16(xh[kc], bl, a, 0, 0, 0);
        }
        if (nt == 0) acc0 = a; else if (nt == 1) acc1 = a; else acc2 = a;
    }

    // -- store q/k (acc0): lanes 0-15 -> q col, 16-31 -> k col
    {
        unsigned short* dst = (col < 16) ? (qb + col) : (kb + (col - 16));
        #pragma unroll
        for (int rr = 0; rr < 16; ++rr) {
            const int grow = row0 + (rr & 3) + 8 * (rr >> 2) + 4 * g;
            dst[(size_t)grow * 16] = f2bf(acc0[rr]);
        }
    }
    // -- store V fragments (acc1: mt=0, acc2: mt=1); wave w owns chunks 2w,2w+1
    {
        const int bb = blockIdx.x >> 6;       // batch
        const int kt = blockIdx.x & 63;       // KV tile
        unsigned short* const vtile = vf + (size_t)(bb * 64 + kt) * 4096;
        #pragma unroll
        for (int mt = 0; mt < 2; ++mt) {
            const f32x16 a = mt ? acc2 : acc1;
            #pragma unroll
            for (int ci = 0; ci < 2; ++ci) {
                I4S8 pk;
                pk.i[0] = cvt_pk_bf16(a[8*ci + 0], a[8*ci + 1]);
                pk.i[1] = cvt_pk_bf16(a[8*ci + 2], a[8*ci + 3]);
                pk.i[2] = cvt_pk_bf16(a[8*ci + 4], a[8*ci + 5]);
                pk.i[3] = cvt_pk_bf16(a[8*ci + 6], a[8*ci + 7]);
                const int c = 2 * w + ci;
                *(s16x8*)(vtile + ((c * 2 + mt) * 64 + lane) * 8) = pk.v;
            }
        }
    }
}

// ---------------------------------------------------------------------------
// One 64-key tile. MODE: 0 = full (no mask), 1 = diag even-i (only first 32
// keys live, triangular), 2 = diag odd-i (first 32 full, second triangular).
// vtile points at this tile's fragment block; all loads fully coalesced.
// ---------------------------------------------------------------------------
template<int MODE>
static __device__ __forceinline__ void do_tile(
    const unsigned short* kp, const unsigned short* vtile, const int lane,
    const s16x8 qf, const int col, const int g,
    f32x16& o0, f32x16& o1, float& lsum)
{
    const int NC = (MODE == 1) ? 2 : 4;   // 16-key chunks for PV
    s16x8 kf0 = *(const s16x8*)(kp);
    s16x8 kf1;
    if (MODE != 1) kf1 = *(const s16x8*)(kp + 512);
    s16x8 va[4][2];
    #pragma unroll
    for (int c = 0; c < NC; ++c)
        #pragma unroll
        for (int mt = 0; mt < 2; ++mt)
            va[c][mt] = *(const s16x8*)(vtile + ((c * 2 + mt) * 64 + lane) * 8);

    f32x16 s0 = __builtin_amdgcn_mfma_f32_32x32x16_bf16(kf0, qf, (f32x16)0.0f, 0, 0, 0);
    f32x16 s1;
    if (MODE != 1) s1 = __builtin_amdgcn_mfma_f32_32x32x16_bf16(kf1, qf, (f32x16)0.0f, 0, 0, 0);

    float e[32];
    float ps[4] = {0.f, 0.f, 0.f, 0.f};
    #pragma unroll
    for (int rr = 0; rr < 16; ++rr) {
        const int drow = (rr & 3) + 8 * (rr >> 2) + 4 * g;
        float e0 = exp2f(s0[rr] - MFIX);
        if (MODE == 1) e0 = (drow <= col) ? e0 : 0.f;
        float e1 = 0.f;
        if (MODE != 1) {
            e1 = exp2f(s1[rr] - MFIX);
            if (MODE == 2) e1 = (drow <= col) ? e1 : 0.f;
        }
        e[rr] = e0;
        e[16 + rr] = e1;
        ps[rr & 3] += e0 + e1;
    }
    lsum += (ps[0] + ps[1]) + (ps[2] + ps[3]);

    int pw[16];
    #pragma unroll
    for (int j = 0; j < (MODE == 1 ? 8 : 16); ++j)
        pw[j] = cvt_pk_bf16(e[2 * j], e[2 * j + 1]);

    #pragma unroll
    for (int mt = 0; mt < 2; ++mt) {
        f32x16 oacc = mt ? o1 : o0;
        #pragma unroll
        for (int c = 0; c < NC; ++c) {
            I4S8 pu;
            pu.i[0] = pw[4 * c + 0]; pu.i[1] = pw[4 * c + 1];
            pu.i[2] = pw[4 * c + 2]; pu.i[3] = pw[4 * c + 3];
            oacc = __builtin_amdgcn_mfma_f32_32x32x16_bf16(va[c][mt], pu.v, oacc, 0, 0, 0);
        }
        if (mt) o1 = oacc; else o0 = oacc;
    }
}

// ---------------------------------------------------------------------------
// Flash attention. 1024 thr = 16 waves; grid (64, NBATCH). Block p does
// q-tiles p and 127-p (65 KV tiles total). Wave w: kt = w, w+16, ...
// Fixed-M => partials merge by SUMMATION (no max merge).
// ---------------------------------------------------------------------------
__global__ __launch_bounds__(1024) void attn_kernel(
    const unsigned short* __restrict__ qb, const unsigned short* __restrict__ kb,
    const unsigned short* __restrict__ vf, float* __restrict__ out)
{
    __shared__ float pl[16][32];
    __shared__ __align__(16) float pO[2048][18];  // [dv*32+q][ww], 144 KB
    __shared__ float outS[32][66];                // store bounce (coalescing)

    const int tid  = threadIdx.x;
    const int w    = tid >> 6;
    const int lane = tid & 63;
    const int col  = lane & 31;
    const int g    = lane >> 5;
    const int b    = blockIdx.y;
    const int p    = blockIdx.x;

    const unsigned short* const kbase = kb + (size_t)b * TSEQ * 16;
    const unsigned short* const vbase = vf + (size_t)b * 64 * 4096;

    for (int half = 0; half < 2; ++half) {
        const int i  = half ? (127 - p) : p;
        const int q0 = i * 32;
        const int n  = (i + 2) >> 1;          // tiles covering keys 0..q0+31

        const s16x8 qf = *(const s16x8*)(qb + ((size_t)(b * TSEQ) + q0 + col) * 16 + 8 * g);

        f32x16 o0 = (f32x16)0.0f, o1 = (f32x16)0.0f;
        float lsum = 0.f;

        int kt = w;
        for (; kt + 1 < n; kt += 16) {
            do_tile<0>(kbase + ((size_t)((kt << 6) + col)) * 16 + 8 * g,
                       vbase + (size_t)kt * 4096, lane, qf, col, g, o0, o1, lsum);
        }
        if (kt == n - 1) {                    // this wave owns the diagonal tile
            const unsigned short* kp = kbase + ((size_t)((kt << 6) + col)) * 16 + 8 * g;
            const unsigned short* vtile = vbase + (size_t)kt * 4096;
            if (i & 1) do_tile<2>(kp, vtile, lane, qf, col, g, o0, o1, lsum);
            else       do_tile<1>(kp, vtile, lane, qf, col, g, o0, o1, lsum);
        }
        lsum += __shfl_xor(lsum, 32);

        // -- write partials (idle waves write zeros: harmless under summation)
        if (g == 0) pl[w][col] = lsum;
        #pragma unroll
        for (int mt = 0; mt < 2; ++mt) {
            const f32x16 oa = mt ? o1 : o0;
            #pragma unroll
            for (int rr = 0; rr < 16; ++rr) {
                const int dv = mt * 32 + (rr & 3) + 8 * (rr >> 2) + 4 * g;
                pO[dv * 32 + col][w] = oa[rr];
            }
        }
        __syncthreads();

        // -- 16-way sum merge: thread handles (q = tid&31, dv = tid>>5 [+32])
        {
            const int q   = tid & 31;
            const int dvh = tid >> 5;
            float L = 0.f;
            #pragma unroll
            for (int ww = 0; ww < 16; ++ww) L += pl[ww][q];
            const float inv = 1.0f / L;
            #pragma unroll
            for (int pass = 0; pass < 2; ++pass) {
                const int dv = dvh + 32 * pass;
                const float* prow = pO[dv * 32 + q];
                float s = 0.f;
                #pragma unroll
                for (int c = 0; c < 8; ++c) {
                    float2 v2 = *(const float2*)(prow + 2 * c);
                    s += v2.x + v2.y;
                }
                outS[q][dv] = s * inv;
            }
        }
        __syncthreads();

        // -- coalesced store: thread (q2 = tid>>5, dvp = (tid&31)*2)
        {
            const int q2  = tid >> 5;
            const int dvp = (tid & 31) * 2;
            float2 v2 = *(const float2*)&outS[q2][dvp];
            *(float2*)(out + ((size_t)(b * TSEQ) + q0 + q2) * 64 + dvp) = v2;
        }
        // pO reuse in next half is safe: reads completed before the barrier.
    }
}

// ---------------------------------------------------------------------------
extern "C" void kernel_launch(void* const* d_in, const int* in_sizes, int n_in,
                              void* d_out, int out_size, void* d_ws, size_t ws_size,
                              hipStream_t stream) {
    const float* x  = (const float*)d_in[0];
    const float* Wq = (const float*)d_in[1];
    const float* Wk = (const float*)d_in[2];
    const float* Wv = (const float*)d_in[3];

    // workspace: q (512KiB) | k (512KiB) | v-fragments (2MiB) = 3 MiB
    unsigned short* qb = (unsigned short*)d_ws;
    unsigned short* kb = qb + (size_t)NBATCH * TSEQ * 16;
    unsigned short* vf = kb + (size_t)NBATCH * TSEQ * 16;
    float* out = (float*)d_out;

    proj_kernel<<<dim3((NBATCH * TSEQ) / 64), 128, 0, stream>>>(x, Wq, Wk, Wv, qb, kb, vf);
    attn_kernel<<<dim3(64, NBATCH), 1024, 0, stream>>>(qb, kb, vf, out);
}

// Round 5
// 27.493 us; speedup vs baseline: 1.9839x; 1.1499x over previous
//
#include <hip/hip_runtime.h>

// SelfAttention: x[4,4096,64] f32; Wq,Wk[64,16]; Wv[64,64]; out[4,4096,64] f32.
// proj: bf16 MFMA with exact hi/lo split (f32-faithful), q pre-scaled by
//   1/sqrt(16)*log2e; outputs bf16 q,k row-major and V in MFMA *fragment
//   order* vf[b][kt][c][mt][lane][8] so attention's PV A-operand loads are
//   fully coalesced (64 lanes x 16B = 1KB contiguous per load).
// attn: flash with FIXED softmax max (M=24; scores ~N(0,1.44^2) in log2
//   domain) -> no max tree, no rescale, partials merge by summation.
//   Block = 16 waves (1024 thr), grid (64,4); block p owns q-tile pair
//   (p, 127-p) == exactly 65 KV tiles; waves split KV round-robin.
// R5: fix VGPR starvation. launch_bounds(1024,4) -> 128-VGPR cap (was 64 ->
//   ~60 regs spilled to scratch = the R2-R4 latency wall). do_tile reworked
//   to exponentiate in place in the S accumulator (no e[32] array).

#define TSEQ 4096
#define NBATCH 4
#define MFIX 24.0f

typedef __attribute__((ext_vector_type(4)))  float fvec4;
typedef __attribute__((ext_vector_type(16))) float f32x16;
typedef __attribute__((ext_vector_type(8)))  short s16x8;

union I4S8 { int i[4]; s16x8 v; };

static __device__ __forceinline__ unsigned short f2bf(float f) {
    unsigned u = __float_as_uint(f);
    u += 0x7FFFu + ((u >> 16) & 1u);   // RNE
    return (unsigned short)(u >> 16);
}

static __device__ __forceinline__ int cvt_pk_bf16(float lo, float hi) {
    int r;
    asm("v_cvt_pk_bf16_f32 %0, %1, %2" : "=v"(r) : "v"(lo), "v"(hi));
    return r;
}

// ---------------------------------------------------------------------------
// Projection via MFMA. Block = 256 thr (4 waves) = 128 x-rows = two attn KV
// tiles; grid 128. x = xh+xl, W = Wh+Wl (bf16 splits, exact);
// x@W ~= xh·Wh + xh·Wl + xl·Wh  (dropped xl·Wl ~ 2^-18 relative).
// D-layout per lane == attn A-frag layout, so V stores go out in fragment
// order with no cross-lane ops.
// ---------------------------------------------------------------------------
__global__ __launch_bounds__(256, 2) void proj_kernel(
    const float* __restrict__ x,  const float* __restrict__ Wq,
    const float* __restrict__ Wk, const float* __restrict__ Wv,
    unsigned short* __restrict__ qb, unsigned short* __restrict__ kb,
    unsigned short* __restrict__ vf)
{
    __shared__ __align__(16) unsigned short Wh[96][72], Wl[96][72]; // [n][k]
    const int tid  = threadIdx.x;
    const int w    = tid >> 6;
    const int lane = tid & 63;
    const int col  = lane & 31;
    const int g    = lane >> 5;

    const float SCQ = 0.25f * 1.44269504088896340736f; // 1/sqrt(16)*log2(e)
    // -- coalesced W staging: Wq/Wk are [k][16], Wv is [k][64] row-major
    #pragma unroll
    for (int j = 0; j < 4; ++j) {
        const int idx = tid + 256 * j;            // 0..1023
        const int n = idx & 15, k = idx >> 4;
        float wv = Wq[idx] * SCQ;
        unsigned short h = f2bf(wv);
        Wh[n][k] = h;
        Wl[n][k] = f2bf(wv - __uint_as_float((unsigned)h << 16));
    }
    #pragma unroll
    for (int j = 0; j < 4; ++j) {
        const int idx = tid + 256 * j;
        const int n = idx & 15, k = idx >> 4;
        float wv = Wk[idx];
        unsigned short h = f2bf(wv);
        Wh[16 + n][k] = h;
        Wl[16 + n][k] = f2bf(wv - __uint_as_float((unsigned)h << 16));
    }
    #pragma unroll
    for (int j = 0; j < 16; ++j) {
        const int idx = tid + 256 * j;            // 0..4095
        const int n = idx & 63, k = idx >> 6;
        float wv = Wv[idx];
        unsigned short h = f2bf(wv);
        Wh[32 + n][k] = h;
        Wl[32 + n][k] = f2bf(wv - __uint_as_float((unsigned)h << 16));
    }
    __syncthreads();

    const int row0 = blockIdx.x * 128 + w * 32;
    const int arow = row0 + col;

    s16x8 xh[4], xl[4];
    #pragma unroll
    for (int kc = 0; kc < 4; ++kc) {
        const float* xp = x + (size_t)arow * 64 + kc * 16 + 8 * g;
        fvec4 xa = *(const fvec4*)(xp);
        fvec4 xb = *(const fvec4*)(xp + 4);
        I4S8 uh, ul;
        uh.i[0] = cvt_pk_bf16(xa[0], xa[1]);
        uh.i[1] = cvt_pk_bf16(xa[2], xa[3]);
        uh.i[2] = cvt_pk_bf16(xb[0], xb[1]);
        uh.i[3] = cvt_pk_bf16(xb[2], xb[3]);
        float l0 = xa[0] - __uint_as_float((unsigned)uh.i[0] << 16);
        float l1 = xa[1] - __uint_as_float((unsigned)uh.i[0] & 0xffff0000u);
        float l2 = xa[2] - __uint_as_float((unsigned)uh.i[1] << 16);
        float l3 = xa[3] - __uint_as_float((unsigned)uh.i[1] & 0xffff0000u);
        float l4 = xb[0] - __uint_as_float((unsigned)uh.i[2] << 16);
        float l5 = xb[1] - __uint_as_float((unsigned)uh.i[2] & 0xffff0000u);
        float l6 = xb[2] - __uint_as_float((unsigned)uh.i[3] << 16);
        float l7 = xb[3] - __uint_as_float((unsigned)uh.i[3] & 0xffff0000u);
        ul.i[0] = cvt_pk_bf16(l0, l1);
        ul.i[1] = cvt_pk_bf16(l2, l3);
        ul.i[2] = cvt_pk_bf16(l4, l5);
        ul.i[3] = cvt_pk_bf16(l6, l7);
        xh[kc] = uh.v; xl[kc] = ul.v;
    }

    f32x16 acc0 = (f32x16)0.0f, acc1 = (f32x16)0.0f, acc2 = (f32x16)0.0f;
    #pragma unroll
    for (int nt = 0; nt < 3; ++nt) {
        const int n = nt * 32 + col;
        f32x16 a = nt == 0 ? acc0 : (nt == 1 ? acc1 : acc2);
        #pragma unroll
        for (int kc = 0; kc < 4; ++kc) {
            s16x8 bh = *(const s16x8*)&Wh[n][kc * 16 + 8 * g];
            s16x8 bl = *(const s16x8*)&Wl[n][kc * 16 + 8 * g];
            a = __builtin_amdgcn_mfma_f32_32x32x16_bf16(xh[kc], bh, a, 0, 0, 0);
            a = __builtin_amdgcn_mfma_f32_32x32x16_bf16(xl[kc], bh, a, 0, 0, 0);
            a = __builtin_amdgcn_mfma_f32_32x32x16_bf16(xh[kc], bl, a, 0, 0, 0);
        }
        if (nt == 0) acc0 = a; else if (nt == 1) acc1 = a; else acc2 = a;
    }

    // -- store q/k (acc0): lanes 0-15 -> q col, 16-31 -> k col
    {
        unsigned short* dst = (col < 16) ? (qb + col) : (kb + (col - 16));
        #pragma unroll
        for (int rr = 0; rr < 16; ++rr) {
            const int grow = row0 + (rr & 3) + 8 * (rr >> 2) + 4 * g;
            dst[(size_t)grow * 16] = f2bf(acc0[rr]);
        }
    }
    // -- store V fragments (acc1: mt=0, acc2: mt=1)
    {
        const int tile = row0 >> 6;           // == b*64 + kt
        const int hw   = (row0 >> 5) & 1;     // which tile-half this wave is
        unsigned short* const vtile = vf + (size_t)tile * 4096;
        #pragma unroll
        for (int mt = 0; mt < 2; ++mt) {
            const f32x16 a = mt ? acc2 : acc1;
            #pragma unroll
            for (int ci = 0; ci < 2; ++ci) {
                I4S8 pk;
                pk.i[0] = cvt_pk_bf16(a[8*ci + 0], a[8*ci + 1]);
                pk.i[1] = cvt_pk_bf16(a[8*ci + 2], a[8*ci + 3]);
                pk.i[2] = cvt_pk_bf16(a[8*ci + 4], a[8*ci + 5]);
                pk.i[3] = cvt_pk_bf16(a[8*ci + 6], a[8*ci + 7]);
                const int c = 2 * hw + ci;
                *(s16x8*)(vtile + ((c * 2 + mt) * 64 + lane) * 8) = pk.v;
            }
        }
    }
}

// ---------------------------------------------------------------------------
// One 64-key tile. MODE: 0 = full (no mask), 1 = diag even-i (only first 32
// keys live, triangular), 2 = diag odd-i (first 32 full, second triangular).
// Exponentiation is IN PLACE in the S accumulators (no e[] array) to keep
// peak live registers < 128.
// ---------------------------------------------------------------------------
template<int MODE>
static __device__ __forceinline__ void do_tile(
    const unsigned short* kp, const unsigned short* vtile, const int lane,
    const s16x8 qf, const int col, const int g,
    f32x16& o0, f32x16& o1, float& lsum)
{
    const int NC = (MODE == 1) ? 2 : 4;   // 16-key chunks for PV
    s16x8 kf0 = *(const s16x8*)(kp);
    s16x8 kf1;
    if (MODE != 1) kf1 = *(const s16x8*)(kp + 512);
    s16x8 va[4][2];
    #pragma unroll
    for (int c = 0; c < NC; ++c) {
        va[c][0] = *(const s16x8*)(vtile + ((c * 2 + 0) * 64 + lane) * 8);
        va[c][1] = *(const s16x8*)(vtile + ((c * 2 + 1) * 64 + lane) * 8);
    }
    f32x16 s0 = __builtin_amdgcn_mfma_f32_32x32x16_bf16(kf0, qf, (f32x16)0.0f, 0, 0, 0);
    f32x16 s1;
    if (MODE != 1) s1 = __builtin_amdgcn_mfma_f32_32x32x16_bf16(kf1, qf, (f32x16)0.0f, 0, 0, 0);

    int pw[16];
    float psA = 0.f, psB = 0.f, psC = 0.f, psD = 0.f;
    // -- half 0 (keys k0..k0+31): exp in place, then pack
    #pragma unroll
    for (int rr = 0; rr < 16; ++rr) {
        float ev = __builtin_amdgcn_exp2f(s0[rr] - MFIX);
        if (MODE == 1) {
            const int drow = (rr & 3) + 8 * (rr >> 2) + 4 * g;
            ev = (drow <= col) ? ev : 0.f;
        }
        s0[rr] = ev;
        if ((rr & 3) == 0) psA += ev; else if ((rr & 3) == 1) psB += ev;
        else if ((rr & 3) == 2) psC += ev; else psD += ev;
    }
    #pragma unroll
    for (int j = 0; j < 8; ++j) pw[j] = cvt_pk_bf16(s0[2*j], s0[2*j+1]);
    // -- half 1 (keys k0+32..k0+63)
    if (MODE != 1) {
        #pragma unroll
        for (int rr = 0; rr < 16; ++rr) {
            float ev = __builtin_amdgcn_exp2f(s1[rr] - MFIX);
            if (MODE == 2) {
                const int drow = (rr & 3) + 8 * (rr >> 2) + 4 * g;
                ev = (drow <= col) ? ev : 0.f;
            }
            s1[rr] = ev;
            if ((rr & 3) == 0) psA += ev; else if ((rr & 3) == 1) psB += ev;
            else if ((rr & 3) == 2) psC += ev; else psD += ev;
        }
        #pragma unroll
        for (int j = 0; j < 8; ++j) pw[8 + j] = cvt_pk_bf16(s1[2*j], s1[2*j+1]);
    }
    lsum += (psA + psB) + (psC + psD);

    // -- O^T += V^T * P^T
    #pragma unroll
    for (int mt = 0; mt < 2; ++mt) {
        f32x16 oacc = mt ? o1 : o0;
        #pragma unroll
        for (int c = 0; c < NC; ++c) {
            I4S8 pu;
            pu.i[0] = pw[4 * c + 0]; pu.i[1] = pw[4 * c + 1];
            pu.i[2] = pw[4 * c + 2]; pu.i[3] = pw[4 * c + 3];
            oacc = __builtin_amdgcn_mfma_f32_32x32x16_bf16(va[c][mt], pu.v, oacc, 0, 0, 0);
        }
        if (mt) o1 = oacc; else o0 = oacc;
    }
}

// ---------------------------------------------------------------------------
// Flash attention. 1024 thr = 16 waves; grid (64, NBATCH). Block p does
// q-tiles p and 127-p (65 KV tiles total). Wave w: kt = w, w+16, ...
// Fixed-M => partials merge by SUMMATION (no max merge).
// launch_bounds(1024, 4): 4 waves/EU min -> VGPR cap 128 (NOT 64 -> no spill).
// ---------------------------------------------------------------------------
__global__ __launch_bounds__(1024, 4) void attn_kernel(
    const unsigned short* __restrict__ qb, const unsigned short* __restrict__ kb,
    const unsigned short* __restrict__ vf, float* __restrict__ out)
{
    __shared__ float pl[16][32];
    __shared__ __align__(16) float pO[2048][18];  // [dv*32+q][ww], 144 KB
    __shared__ float outS[32][66];                // store bounce (coalescing)

    const int tid  = threadIdx.x;
    const int w    = tid >> 6;
    const int lane = tid & 63;
    const int col  = lane & 31;
    const int g    = lane >> 5;
    const int b    = blockIdx.y;
    const int p    = blockIdx.x;

    const unsigned short* const kbase = kb + (size_t)b * TSEQ * 16;
    const unsigned short* const vbase = vf + (size_t)b * 64 * 4096;

    for (int half = 0; half < 2; ++half) {
        const int i  = half ? (127 - p) : p;
        const int q0 = i * 32;
        const int n  = (i + 2) >> 1;          // tiles covering keys 0..q0+31

        const s16x8 qf = *(const s16x8*)(qb + ((size_t)(b * TSEQ) + q0 + col) * 16 + 8 * g);

        f32x16 o0 = (f32x16)0.0f, o1 = (f32x16)0.0f;
        float lsum = 0.f;

        int kt = w;
        for (; kt + 1 < n; kt += 16) {
            do_tile<0>(kbase + ((size_t)((kt << 6) + col)) * 16 + 8 * g,
                       vbase + (size_t)kt * 4096, lane, qf, col, g, o0, o1, lsum);
        }
        if (kt == n - 1) {                    // this wave owns the diagonal tile
            const unsigned short* kp = kbase + ((size_t)((kt << 6) + col)) * 16 + 8 * g;
            const unsigned short* vtile = vbase + (size_t)kt * 4096;
            if (i & 1) do_tile<2>(kp, vtile, lane, qf, col, g, o0, o1, lsum);
            else       do_tile<1>(kp, vtile, lane, qf, col, g, o0, o1, lsum);
        }
        lsum += __shfl_xor(lsum, 32);

        // -- write partials (idle waves write zeros: harmless under summation)
        if (g == 0) pl[w][col] = lsum;
        #pragma unroll
        for (int mt = 0; mt < 2; ++mt) {
            const f32x16 oa = mt ? o1 : o0;
            #pragma unroll
            for (int rr = 0; rr < 16; ++rr) {
                const int dv = mt * 32 + (rr & 3) + 8 * (rr >> 2) + 4 * g;
                pO[dv * 32 + col][w] = oa[rr];
            }
        }
        __syncthreads();

        // -- 16-way sum merge: thread handles (q = tid&31, dv = tid>>5 [+32])
        {
            const int q   = tid & 31;
            const int dvh = tid >> 5;
            float L = 0.f;
            #pragma unroll
            for (int ww = 0; ww < 16; ++ww) L += pl[ww][q];
            const float inv = 1.0f / L;
            #pragma unroll
            for (int pass = 0; pass < 2; ++pass) {
                const int dv = dvh + 32 * pass;
                const float* prow = pO[dv * 32 + q];
                float s = 0.f;
                #pragma unroll
                for (int c = 0; c < 8; ++c) {
                    float2 v2 = *(const float2*)(prow + 2 * c);
                    s += v2.x + v2.y;
                }
                outS[q][dv] = s * inv;
            }
        }
        __syncthreads();

        // -- coalesced store: thread (q2 = tid>>5, dvp = (tid&31)*2)
        {
            const int q2  = tid >> 5;
            const int dvp = (tid & 31) * 2;
            float2 v2 = *(const float2*)&outS[q2][dvp];
            *(float2*)(out + ((size_t)(b * TSEQ) + q0 + q2) * 64 + dvp) = v2;
        }
        // pO reuse in next half is safe: reads completed before the barrier.
    }
}

// ---------------------------------------------------------------------------
extern "C" void kernel_launch(void* const* d_in, const int* in_sizes, int n_in,
                              void* d_out, int out_size, void* d_ws, size_t ws_size,
                              hipStream_t stream) {
    const float* x  = (const float*)d_in[0];
    const float* Wq = (const float*)d_in[1];
    const float* Wk = (const float*)d_in[2];
    const float* Wv = (const float*)d_in[3];

    // workspace: q (512KiB) | k (512KiB) | v-fragments (2MiB) = 3 MiB
    unsigned short* qb = (unsigned short*)d_ws;
    unsigned short* kb = qb + (size_t)NBATCH * TSEQ * 16;
    unsigned short* vf = kb + (size_t)NBATCH * TSEQ * 16;
    float* out = (float*)d_out;

    proj_kernel<<<dim3((NBATCH * TSEQ) / 128), 256, 0, stream>>>(x, Wq, Wk, Wv, qb, kb, vf);
    attn_kernel<<<dim3(64, NBATCH), 1024, 0, stream>>>(qb, kb, vf, out);
}